// Round 2
// baseline (62.738 us; speedup 1.0000x reference)
//
#include <hip/hip_runtime.h>

#ifndef EB_V
#define EB_V 100000
#endif
#ifndef EB_D
#define EB_D 128
#endif

// Kernel 1: rowsum[v] = 5*sum(W0[v,:]) + 10*sum(W1[v,:]) + 6*sum(W2[v,:])
// 256 threads/block = 4 waves = 8 half-wave (32-lane) groups; one row per group.
// Each lane loads one float4 per table -> 32 lanes * 16B = 512B = full row, coalesced.
__global__ __launch_bounds__(256) void eb_rowsum_kernel(
    const float* __restrict__ W0,
    const float* __restrict__ W1,
    const float* __restrict__ W2,
    float* __restrict__ rowsum,
    int nrows)
{
    const int tid    = threadIdx.x;
    const int lane32 = tid & 31;
    const int group  = tid >> 5;                 // 0..7
    const int v      = blockIdx.x * 8 + group;
    if (v >= nrows) return;

    const size_t rowbase = (size_t)v * EB_D;
    const float4 a = ((const float4*)(W0 + rowbase))[lane32];
    const float4 b = ((const float4*)(W1 + rowbase))[lane32];
    const float4 c = ((const float4*)(W2 + rowbase))[lane32];

    float s = 5.0f  * (a.x + a.y + a.z + a.w)
            + 10.0f * (b.x + b.y + b.z + b.w)
            + 6.0f  * (c.x + c.y + c.z + c.w);

    // Reduce within each 32-lane group (masks 1..16 stay inside each half of wave64).
    #pragma unroll
    for (int m = 16; m >= 1; m >>= 1) s += __shfl_xor(s, m, 64);

    if (lane32 == 0) rowsum[v] = s;
}

// Kernel 2: out += sum_i rowsum[idx[i]]  (idx is int32 per harness convention)
__global__ __launch_bounds__(256) void eb_gather_reduce_kernel(
    const int* __restrict__ idx,
    const float* __restrict__ rowsum,
    float* __restrict__ out,
    int n, int nrows)
{
    float acc = 0.0f;
    for (int i = blockIdx.x * blockDim.x + threadIdx.x; i < n;
         i += gridDim.x * blockDim.x) {
        const unsigned v = (unsigned)idx[i];
        if (v < (unsigned)nrows) acc += rowsum[v];   // guard: never fault on bad idx
    }

    // Full-wave (64-lane) butterfly reduce.
    #pragma unroll
    for (int m = 32; m >= 1; m >>= 1) acc += __shfl_xor(acc, m, 64);

    __shared__ float wsum[4];
    const int lane = threadIdx.x & 63;
    const int wid  = threadIdx.x >> 6;
    if (lane == 0) wsum[wid] = acc;
    __syncthreads();
    if (threadIdx.x == 0) {
        atomicAdd(out, wsum[0] + wsum[1] + wsum[2] + wsum[3]);
    }
}

extern "C" void kernel_launch(void* const* d_in, const int* in_sizes, int n_in,
                              void* d_out, int out_size, void* d_ws, size_t ws_size,
                              hipStream_t stream) {
    const int* eb_input = (const int*)d_in[0];   // int32 (harness: integer -> const int*)
    // d_in[1] = eb_offset: mathematically irrelevant (result sums over all bags).
    const float* W0 = (const float*)d_in[2];
    const float* W1 = (const float*)d_in[3];
    const float* W2 = (const float*)d_in[4];

    const int N = in_sizes[0];
    const int nrows = in_sizes[2] / EB_D;   // V

    float* rowsum = (float*)d_ws;           // V floats = 400 KB, fits in ws
    float* out = (float*)d_out;

    // Harness poisons d_out; zero it (memsetAsync is graph-capture-safe).
    hipMemsetAsync(out, 0, (size_t)out_size * sizeof(float), stream);

    // Kernel 1: 8 rows per 256-thread block.
    const int blocks1 = (nrows + 7) / 8;
    eb_rowsum_kernel<<<blocks1, 256, 0, stream>>>(W0, W1, W2, rowsum, nrows);

    // Kernel 2: grid-stride over N indices, capped grid.
    int blocks2 = (N + 255) / 256;
    if (blocks2 > 2048) blocks2 = 2048;
    eb_gather_reduce_kernel<<<blocks2, 256, 0, stream>>>(eb_input, rowsum, out, N, nrows);
}